// Round 1
// baseline (777.153 us; speedup 1.0000x reference)
//
#include <hip/hip_runtime.h>
#include <math.h>

#define NROW 1024
#define TILE 128
#define INFHI 0x7FF00000u

__device__ __forceinline__ unsigned long long umin64(unsigned long long a, unsigned long long b) {
    return a < b ? a : b;
}

// Per-row exact top-16 selection on f64 d2 values stored as (hi,lo) 32-bit words.
// Bisection on hi word via ballot counting; ties at the boundary hi word resolved
// by (lo word, j) with lowest-(value,index) priority, matching jax.lax.top_k.
#define ROW_SELECT(H, L, SELOUT)                                                        \
    {                                                                                   \
        unsigned mn = 0xFFFFFFFFu, mx = 0u;                                             \
        _Pragma("unroll")                                                               \
        for (int r = 0; r < 16; ++r) {                                                  \
            mn = (H[r] < mn) ? H[r] : mn;                                               \
            unsigned hf = (H[r] < INFHI) ? H[r] : 0u;                                   \
            mx = (hf > mx) ? hf : mx;                                                   \
        }                                                                               \
        for (int dlt = 1; dlt < 64; dlt <<= 1) {                                        \
            unsigned omn = (unsigned)__shfl_xor((int)mn, dlt);                          \
            unsigned omx = (unsigned)__shfl_xor((int)mx, dlt);                          \
            mn = (omn < mn) ? omn : mn;                                                 \
            mx = (omx > mx) ? omx : mx;                                                 \
        }                                                                               \
        int cntF = 0;                                                                   \
        _Pragma("unroll")                                                               \
        for (int r = 0; r < 16; ++r) cntF += __popcll(__ballot(H[r] < INFHI));          \
        unsigned smask = 0u, eqsel = 0u;                                                \
        if (cntF < 16) {                                                                \
            _Pragma("unroll")                                                           \
            for (int r = 0; r < 16; ++r) smask |= (H[r] < INFHI ? 1u : 0u) << r;        \
        } else {                                                                        \
            unsigned blo = mn, bhi = mx + 1u;                                           \
            while (bhi - blo > 1u) {                                                    \
                unsigned mid = blo + ((bhi - blo) >> 1);                                \
                int cnt = 0;                                                            \
                _Pragma("unroll")                                                       \
                for (int r = 0; r < 16; ++r) cnt += __popcll(__ballot(H[r] < mid));     \
                if (cnt >= 16) bhi = mid; else blo = mid;                               \
            }                                                                           \
            const unsigned Vhi = blo;                                                   \
            int cS = 0, nE = 0;                                                         \
            unsigned eqm = 0u;                                                          \
            _Pragma("unroll")                                                           \
            for (int r = 0; r < 16; ++r) {                                              \
                cS += __popcll(__ballot(H[r] < Vhi));                                   \
                const bool e = (H[r] == Vhi);                                           \
                nE += __popcll(__ballot(e));                                            \
                eqm |= (e ? 1u : 0u) << r;                                              \
                smask |= (H[r] < Vhi ? 1u : 0u) << r;                                   \
            }                                                                           \
            const int extra = 16 - cS;                                                  \
            if (nE == extra) {                                                          \
                eqsel = eqm;                                                            \
            } else {                                                                    \
                for (int it = 0; it < extra; ++it) {                                    \
                    unsigned long long bk = ~0ull;                                      \
                    int br = -1;                                                        \
                    _Pragma("unroll")                                                   \
                    for (int r = 0; r < 16; ++r) {                                      \
                        if (((eqm >> r) & 1u) && !((eqsel >> r) & 1u)) {                \
                            unsigned long long k =                                      \
                                ((unsigned long long)L[r] << 10) |                      \
                                (unsigned long long)(unsigned)(r * 64 + lane);          \
                            if (k < bk) { bk = k; br = r; }                             \
                        }                                                               \
                    }                                                                   \
                    unsigned long long g = bk;                                          \
                    for (int dlt = 1; dlt < 64; dlt <<= 1)                              \
                        g = umin64(g, __shfl_xor(g, dlt));                              \
                    if (g != ~0ull && bk == g && br >= 0) eqsel |= 1u << br;            \
                }                                                                       \
            }                                                                           \
        }                                                                               \
        SELOUT = smask | eqsel;                                                         \
    }

__global__ __launch_bounds__(256) void edge_knn_kernel(
    const float* __restrict__ nodes,
    const int*   __restrict__ mask,
    float*       __restrict__ out)
{
    const int tid  = threadIdx.x;
    const int lane = tid & 63;
    const int wid  = tid >> 6;
    const int blk  = blockIdx.x;
    const int b    = blk >> 7;                 // 128 blocks per batch
    const int rowbase = (blk & 127) * 8;       // 8 rows per block

    const int* maskb = mask + b * NROW;
    float* edges = out + (size_t)b * NROW * NROW;
    float* adjm  = out + (size_t)64 * NROW * NROW + (size_t)b * NROW * NROW;

    // ---- fast path: all 8 rows masked out -> pure zero-fill (must still write; d_out is poisoned)
    int anyv = 0;
#pragma unroll
    for (int r = 0; r < 8; ++r) anyv |= maskb[rowbase + r];
    if (!anyv) {
        const float4 z = make_float4(0.f, 0.f, 0.f, 0.f);
#pragma unroll
        for (int r = 0; r < 8; ++r) {
            float4* e4 = reinterpret_cast<float4*>(edges + (size_t)(rowbase + r) * NROW);
            float4* a4 = reinterpret_cast<float4*>(adjm  + (size_t)(rowbase + r) * NROW);
            for (int k = tid; k < NROW / 4; k += 256) { e4[k] = z; a4[k] = z; }
        }
        return;
    }

    // swizzled column-coord tile: column c, float4 f stored at [c*8 + (f ^ (c&7))]
    __shared__ float4 tile[TILE * 8];   // 16 KB
    __shared__ double sqd[TILE];        // per-column |cj|^2 (f64)

    const int i0 = rowbase + wid * 2;
    const int i1 = i0 + 1;
    const bool rv0 = maskb[i0] != 0;
    const bool rv1 = maskb[i1] != 0;

    const float4* cip0 = reinterpret_cast<const float4*>(nodes + ((size_t)b * NROW + i0) * 64);
    const float4* cip1 = reinterpret_cast<const float4*>(nodes + ((size_t)b * NROW + i1) * 64);
    float4 a0f[8], a1f[8];
#pragma unroll
    for (int f = 0; f < 8; ++f) { a0f[f] = cip0[f]; a1f[f] = cip1[f]; }

    double sqi0 = 0.0, sqi1 = 0.0;
#pragma unroll
    for (int f = 0; f < 8; ++f) {
        sqi0 += (double)a0f[f].x * a0f[f].x + (double)a0f[f].y * a0f[f].y
              + (double)a0f[f].z * a0f[f].z + (double)a0f[f].w * a0f[f].w;
        sqi1 += (double)a1f[f].x * a1f[f].x + (double)a1f[f].y * a1f[f].y
              + (double)a1f[f].z * a1f[f].z + (double)a1f[f].w * a1f[f].w;
    }

    // column validity bits for this lane: bit r <-> column j = 64*r + lane
    unsigned mb = 0;
#pragma unroll
    for (int r = 0; r < 16; ++r) mb |= (maskb[r * 64 + lane] != 0 ? 1u : 0u) << r;

    unsigned h0[16], l0[16], h1[16], l1[16];
    const float* nbase = nodes + (size_t)b * NROW * 64;

#pragma unroll
    for (int t = 0; t < 8; ++t) {
        const int c0col = t * TILE;
        __syncthreads();   // guard LDS reuse from previous tile
        // stage 128 cols x 32 floats, swizzled, coalesced 16B loads
#pragma unroll
        for (int q = 0; q < 4; ++q) {
            const int slot = q * 256 + tid;
            const int c  = slot >> 3;
            const int fp = slot & 7;
            const int f  = fp ^ (c & 7);
            tile[slot] = *reinterpret_cast<const float4*>(nbase + (size_t)(c0col + c) * 64 + f * 4);
        }
        __syncthreads();
        // per-column squared norms in f64 (shared across the block's 8 rows)
        if (tid < TILE) {
            const int c = tid;
            double s = 0.0;
#pragma unroll
            for (int f = 0; f < 8; ++f) {
                const float4 v = tile[c * 8 + (f ^ (c & 7))];
                s += (double)v.x * v.x + (double)v.y * v.y + (double)v.z * v.z + (double)v.w * v.w;
            }
            sqd[c] = s;
        }
        __syncthreads();

        // each lane: 2 columns (lane, 64+lane) x 2 rows, f64 dot products
        double dot00 = 0.0, dot01 = 0.0, dot10 = 0.0, dot11 = 0.0;
        const int swz = lane & 7;   // (64+lane)&7 == lane&7
#pragma unroll
        for (int f = 0; f < 8; ++f) {
            const float4 vA = tile[lane * 8 + (f ^ swz)];
            const float4 vB = tile[(64 + lane) * 8 + (f ^ swz)];
            const double ax = a0f[f].x, ay = a0f[f].y, az = a0f[f].z, aw = a0f[f].w;
            const double bx = a1f[f].x, by = a1f[f].y, bz = a1f[f].z, bw = a1f[f].w;
            const double vax = vA.x, vay = vA.y, vaz = vA.z, vaw = vA.w;
            const double vbx = vB.x, vby = vB.y, vbz = vB.z, vbw = vB.w;
            dot00 = fma(vax, ax, dot00); dot00 = fma(vay, ay, dot00);
            dot00 = fma(vaz, az, dot00); dot00 = fma(vaw, aw, dot00);
            dot01 = fma(vbx, ax, dot01); dot01 = fma(vby, ay, dot01);
            dot01 = fma(vbz, az, dot01); dot01 = fma(vbw, aw, dot01);
            dot10 = fma(vax, bx, dot10); dot10 = fma(vay, by, dot10);
            dot10 = fma(vaz, bz, dot10); dot10 = fma(vaw, bw, dot10);
            dot11 = fma(vbx, bx, dot11); dot11 = fma(vby, by, dot11);
            dot11 = fma(vbz, bz, dot11); dot11 = fma(vbw, bw, dot11);
        }

        const double sqA = sqd[lane];
        const double sqB = sqd[64 + lane];
        {
            const int r = t * 2;
            const int j = c0col + lane;
            double d2 = fma(-2.0, dot00, sqi0 + sqA); d2 = fmax(d2, 1e-12);
            if (!(((mb >> r) & 1u) && (j != i0))) d2 = __builtin_inf();
            h0[r] = (unsigned)__double2hiint(d2); l0[r] = (unsigned)__double2loint(d2);
            double e2 = fma(-2.0, dot10, sqi1 + sqA); e2 = fmax(e2, 1e-12);
            if (!(((mb >> r) & 1u) && (j != i1))) e2 = __builtin_inf();
            h1[r] = (unsigned)__double2hiint(e2); l1[r] = (unsigned)__double2loint(e2);
        }
        {
            const int r = t * 2 + 1;
            const int j = c0col + 64 + lane;
            double d2 = fma(-2.0, dot01, sqi0 + sqB); d2 = fmax(d2, 1e-12);
            if (!(((mb >> r) & 1u) && (j != i0))) d2 = __builtin_inf();
            h0[r] = (unsigned)__double2hiint(d2); l0[r] = (unsigned)__double2loint(d2);
            double e2 = fma(-2.0, dot11, sqi1 + sqB); e2 = fmax(e2, 1e-12);
            if (!(((mb >> r) & 1u) && (j != i1))) e2 = __builtin_inf();
            h1[r] = (unsigned)__double2hiint(e2); l1[r] = (unsigned)__double2loint(e2);
        }
    }

    // ---- per-row exact top-16 selection (wave-uniform branches; ballots see full wave)
    unsigned sel0 = 0u, sel1 = 0u;
    if (rv0) ROW_SELECT(h0, l0, sel0);
    if (rv1) ROW_SELECT(h1, l1, sel1);

    // ---- dense output write (coalesced dword stores, every element written)
#pragma unroll
    for (int r = 0; r < 16; ++r) {
        const int j = r * 64 + lane;
        {
            float dv = 0.f, av = 0.f;
            if (rv0 && ((sel0 >> r) & 1u)) {
                const double d2 = __hiloint2double((int)h0[r], (int)l0[r]);
                dv = sqrtf((float)d2);
                av = 1.f;
            }
            edges[(size_t)i0 * NROW + j] = dv;
            adjm [(size_t)i0 * NROW + j] = av;
        }
        {
            float dv = 0.f, av = 0.f;
            if (rv1 && ((sel1 >> r) & 1u)) {
                const double d2 = __hiloint2double((int)h1[r], (int)l1[r]);
                dv = sqrtf((float)d2);
                av = 1.f;
            }
            edges[(size_t)i1 * NROW + j] = dv;
            adjm [(size_t)i1 * NROW + j] = av;
        }
    }
}

extern "C" void kernel_launch(void* const* d_in, const int* in_sizes, int n_in,
                              void* d_out, int out_size, void* d_ws, size_t ws_size,
                              hipStream_t stream)
{
    const float* nodes = (const float*)d_in[0];
    const int*   mask  = (const int*)d_in[1];
    float* out = (float*)d_out;

    dim3 grid(64 * 128);   // 64 batches x 128 blocks (8 rows each)
    dim3 block(256);
    hipLaunchKernelGGL(edge_knn_kernel, grid, block, 0, stream, nodes, mask, out);
}